// Round 9
// baseline (1856.591 us; speedup 1.0000x reference)
//
#include <hip/hip_runtime.h>

#define TT 512
#define NB 1024
#define SS 64
#define HH 128
#define NA 10

typedef short bf16x8 __attribute__((ext_vector_type(8)));
typedef float f32x4 __attribute__((ext_vector_type(4)));
typedef unsigned short u16;
typedef unsigned int u32;

__device__ __forceinline__ u16 f2bf(float f){
  union { float f; u32 u; } v; v.f = f;
  return (u16)((v.u + 0x7FFFu + ((v.u >> 16) & 1u)) >> 16);
}
__device__ __forceinline__ float sigm(float v){
  return __builtin_amdgcn_rcpf(1.f + __builtin_amdgcn_exp2f(-1.442695040888963f * v));
}
__device__ __forceinline__ float tanh_(float v){
  return 1.f - 2.f * __builtin_amdgcn_rcpf(1.f + __builtin_amdgcn_exp2f(2.885390081777927f * v));
}
// LDS-commit-only barrier (no vmcnt drain; x prefetch stays in flight)
__device__ __forceinline__ void bar_lds(){
  asm volatile("s_waitcnt lgkmcnt(0)" ::: "memory");
  __builtin_amdgcn_s_barrier();
}

// 64 blocks x 512 threads (8 waves). Block owns batch rows [16b,16b+16) for all T.
// WAVE SPECIALIZATION: waves 0-3 = layer-1 workers, waves 4-7 = layer-2 +
// projection workers, skewed one step:
//   interval t:  L1 waves: h1(t) = LSTM1(x(t), h1(t-1))      [slices w, w+4]
//                L2 waves: h2(t-1) = LSTM2(h1(t-1), h2(t-2)) [slices w-4, w]
//                proj(t-2) on wave 4
// One bar_lds() per interval; every LDS producer->consumer edge crosses exactly 1.
//
// REGISTER-UNION FIX (r7 audit): both roles share ONE set of named register
// arrays (Wr/biasr/cr) loaded with role-specific data, so the allocator sees
// max(192,128)=192 weight VGPRs, not the 320-union of distinct per-role arrays.
//   L1 waves: Wr[si][kt<4] = Whh1 ktile, Wr[si][4+kt] = Wih1 ktile (kt<2)
//   L2 waves: Wr[si][kt<4] = Wih2 ktile; Wr[si][4..5] unused
//
// Fragment layouts (verified r2-r6): A-frag granule: elem (row,j) -> u16
// ((j>>3)*16+row)*8+(j&7); lane L reads 16B at kt*512 + L*8. B-frags (LDS Whh2):
// slice s, kt, gate g at u16 s*8192 + (kt*4+g)*512 + L*8.
__global__ __launch_bounds__(512, 2)
void lstm_fused(const float* __restrict__ x,
                const float* __restrict__ Whh1f,
                const float* __restrict__ bih1, const float* __restrict__ bhh1,
                const float* __restrict__ Wih1f,
                const float* __restrict__ Wih2f,
                const float* __restrict__ Whh2f,
                const float* __restrict__ bih2, const float* __restrict__ bhh2,
                const float* __restrict__ Woutf, const float* __restrict__ boutf,
                float* __restrict__ out)
{
  __shared__ __align__(16) u16 lds[77824];   // 155648 B
  u16* whh2s = lds;            // 65536 u16: Whh2 B-frags
  u16* wos   = lds + 65536;    // 2048: W_out frags
  u16* h1s   = lds + 67584;    // 2 x 2048
  u16* h2s   = lds + 71680;    // 2 x 2048
  u16* xs    = lds + 75776;    // 2 x 1024

  const int tid = threadIdx.x;
  const int w   = tid >> 6;
  const int L   = tid & 63;
  const int Llo = L & 15;
  const int Lhi = L >> 4;
  const int batch0 = blockIdx.x * 16;
  const int afrag = L*8;

  // ---- Whh2 -> LDS B-frags (all threads; r4/r6-verified pattern) ----
#pragma unroll 4
  for (int it = 0; it < 16; ++it){
    int j = it*512 + tid;
    int l = j & 63, g = (j >> 6) & 3, kt = (j >> 8) & 3, ss = (j >> 10) & 7;
    int col = 128*g + 16*ss + (l & 15);
    int k   = kt*32 + (l >> 4)*8;
    const float* s = Whh2f + col*HH + k;
    bf16x8 v;
#pragma unroll
    for (int e = 0; e < 8; ++e) v[e] = (short)f2bf(s[e]);
    *reinterpret_cast<bf16x8*>(&whh2s[j*8]) = v;
  }

  // W_out frags -> LDS
  if (tid < 256){
    int kt = tid >> 6, l = tid & 63, llo = l & 15, lhi = (l >> 4) & 3;
    bf16x8 v;
#pragma unroll
    for (int e = 0; e < 8; ++e) v[e] = 0;
    if (llo < NA){
      const float* s = Woutf + llo*HH + kt*32 + lhi*8;
#pragma unroll
      for (int e = 0; e < 8; ++e) v[e] = (short)f2bf(s[e]);
    }
    *reinterpret_cast<bf16x8*>(&wos[kt*512 + l*8]) = v;
  }

  // zero both h1/h2 buffers
  {
    uint4 z = {0u,0u,0u,0u};
    *reinterpret_cast<uint4*>(h1s + tid*8) = z;
    *reinterpret_cast<uint4*>(h2s + tid*8) = z;
  }

  const float boutr = (Llo < NA) ? boutf[Llo] : 0.f;

  // ---- role-polymorphic register state (SHARED arrays -> union = max) ----
  bf16x8 Wr[2][6][4];      // 192 VGPR
  float  biasr[2][4];
  f32x4  cr[2];
  float4 xreg;

  if (w < 4){
    // L1 worker: slices s = w, w+4
#pragma unroll
    for (int si = 0; si < 2; ++si){
      int s = w + si*4;
#pragma unroll
      for (int kt = 0; kt < 4; ++kt)
#pragma unroll
        for (int g = 0; g < 4; ++g){
          int col = 128*g + 16*s + Llo;
          const float* p = Whh1f + col*HH + kt*32 + Lhi*8;
          bf16x8 v;
#pragma unroll
          for (int e = 0; e < 8; ++e) v[e] = (short)f2bf(p[e]);
          Wr[si][kt][g] = v;
        }
#pragma unroll
      for (int kt = 0; kt < 2; ++kt)
#pragma unroll
        for (int g = 0; g < 4; ++g){
          int col = 128*g + 16*s + Llo;
          const float* p = Wih1f + col*SS + kt*32 + Lhi*8;
          bf16x8 v;
#pragma unroll
          for (int e = 0; e < 8; ++e) v[e] = (short)f2bf(p[e]);
          Wr[si][4+kt][g] = v;
        }
#pragma unroll
      for (int g = 0; g < 4; ++g){
        int col = 128*g + 16*s + Llo;
        biasr[si][g] = bih1[col] + bhh1[col];
      }
    }
    // prologue x staging: row = tid&15, j = (tid>>4)*4
    {
      int row = tid & 15, j = (tid >> 4) * 4;
      int xsIdx = ((j >> 3)*16 + row)*8 + (j & 7);
      float4 xv = *reinterpret_cast<const float4*>(x + ((size_t)(batch0 + row))*SS + j);
      u32 lo = (u32)f2bf(xv.x) | ((u32)f2bf(xv.y) << 16);
      u32 hi = (u32)f2bf(xv.z) | ((u32)f2bf(xv.w) << 16);
      *reinterpret_cast<uint2*>(xs + xsIdx) = make_uint2(lo, hi);
      xreg = *reinterpret_cast<const float4*>(x + ((size_t)NB + batch0 + row)*SS + j);
    }
  } else {
    // L2 worker: slices s = w-4, w
#pragma unroll
    for (int si = 0; si < 2; ++si){
      int s = (w - 4) + si*4;
#pragma unroll
      for (int kt = 0; kt < 4; ++kt)
#pragma unroll
        for (int g = 0; g < 4; ++g){
          int col = 128*g + 16*s + Llo;
          const float* p = Wih2f + col*HH + kt*32 + Lhi*8;
          bf16x8 v;
#pragma unroll
          for (int e = 0; e < 8; ++e) v[e] = (short)f2bf(p[e]);
          Wr[si][kt][g] = v;
        }
#pragma unroll
      for (int g = 0; g < 4; ++g){
        int col = 128*g + 16*s + Llo;
        biasr[si][g] = bih2[col] + bhh2[col];
      }
    }
  }

#pragma unroll
  for (int si = 0; si < 2; ++si) cr[si] = (f32x4){0.f,0.f,0.f,0.f};

  __syncthreads();

  for (int t = 0; t < TT; ++t){
    const u16* h1r = h1s + ((t+1)&1)*2048;   // h1(t-1)
    u16*       h1w = h1s + (t&1)*2048;       // h1(t)
    const u16* h2r = h2s + (t&1)*2048;       // h2(t-2)
    u16*       h2w = h2s + ((t+1)&1)*2048;   // h2(t-1)
    const u16* xsr = xs + (t&1)*1024;        // x(t)
    u16*       xsw = xs + ((t+1)&1)*1024;    // x(t+1)

    if (w < 4){
      // ======== L1 worker: h1(t) = LSTM1(x(t), h1(t-1)) ========
      {
        int row = tid & 15, j = (tid >> 4) * 4;
        int xsIdx = ((j >> 3)*16 + row)*8 + (j & 7);
        u32 lo = (u32)f2bf(xreg.x) | ((u32)f2bf(xreg.y) << 16);
        u32 hi = (u32)f2bf(xreg.z) | ((u32)f2bf(xreg.w) << 16);
        *reinterpret_cast<uint2*>(xsw + xsIdx) = make_uint2(lo, hi);
        if (t + 2 < TT)
          xreg = *reinterpret_cast<const float4*>(x + ((size_t)(t+2)*NB + batch0 + row)*SS + j);
      }
#pragma unroll
      for (int si = 0; si < 2; ++si){
        int s = w + si*4;
        f32x4 a0 = (f32x4){biasr[si][0],biasr[si][0],biasr[si][0],biasr[si][0]};
        f32x4 a1 = (f32x4){biasr[si][1],biasr[si][1],biasr[si][1],biasr[si][1]};
        f32x4 a2 = (f32x4){biasr[si][2],biasr[si][2],biasr[si][2],biasr[si][2]};
        f32x4 a3 = (f32x4){biasr[si][3],biasr[si][3],biasr[si][3],biasr[si][3]};
#pragma unroll
        for (int kt = 0; kt < 4; ++kt){
          bf16x8 hf = *reinterpret_cast<const bf16x8*>(h1r + kt*512 + afrag);
          a0 = __builtin_amdgcn_mfma_f32_16x16x32_bf16(hf, Wr[si][kt][0], a0, 0, 0, 0);
          a1 = __builtin_amdgcn_mfma_f32_16x16x32_bf16(hf, Wr[si][kt][1], a1, 0, 0, 0);
          a2 = __builtin_amdgcn_mfma_f32_16x16x32_bf16(hf, Wr[si][kt][2], a2, 0, 0, 0);
          a3 = __builtin_amdgcn_mfma_f32_16x16x32_bf16(hf, Wr[si][kt][3], a3, 0, 0, 0);
        }
#pragma unroll
        for (int kt = 0; kt < 2; ++kt){
          bf16x8 xf = *reinterpret_cast<const bf16x8*>(xsr + kt*512 + afrag);
          a0 = __builtin_amdgcn_mfma_f32_16x16x32_bf16(xf, Wr[si][4+kt][0], a0, 0, 0, 0);
          a1 = __builtin_amdgcn_mfma_f32_16x16x32_bf16(xf, Wr[si][4+kt][1], a1, 0, 0, 0);
          a2 = __builtin_amdgcn_mfma_f32_16x16x32_bf16(xf, Wr[si][4+kt][2], a2, 0, 0, 0);
          a3 = __builtin_amdgcn_mfma_f32_16x16x32_bf16(xf, Wr[si][4+kt][3], a3, 0, 0, 0);
        }
        int hwIdx = (2*s + (Llo >> 3))*128 + Lhi*32 + (Llo & 7);
#pragma unroll
        for (int r = 0; r < 4; ++r){
          float iv = sigm(a0[r]);
          float fv = sigm(a1[r]);
          float gv = tanh_(a2[r]);
          float ov = sigm(a3[r]);
          float cn = fv*cr[si][r] + iv*gv;
          cr[si][r] = cn;
          h1w[hwIdx + r*8] = f2bf(ov * tanh_(cn));
        }
      }
    } else {
      // ======== L2 worker: h2(t-1) = LSTM2(h1(t-1), h2(t-2)); proj(t-2) ========
#pragma unroll
      for (int si = 0; si < 2; ++si){
        int s = (w - 4) + si*4;
        f32x4 a0 = (f32x4){biasr[si][0],biasr[si][0],biasr[si][0],biasr[si][0]};
        f32x4 a1 = (f32x4){biasr[si][1],biasr[si][1],biasr[si][1],biasr[si][1]};
        f32x4 a2 = (f32x4){biasr[si][2],biasr[si][2],biasr[si][2],biasr[si][2]};
        f32x4 a3 = (f32x4){biasr[si][3],biasr[si][3],biasr[si][3],biasr[si][3]};
#pragma unroll
        for (int kt = 0; kt < 4; ++kt){
          bf16x8 hf1 = *reinterpret_cast<const bf16x8*>(h1r + kt*512 + afrag);
          a0 = __builtin_amdgcn_mfma_f32_16x16x32_bf16(hf1, Wr[si][kt][0], a0, 0, 0, 0);
          a1 = __builtin_amdgcn_mfma_f32_16x16x32_bf16(hf1, Wr[si][kt][1], a1, 0, 0, 0);
          a2 = __builtin_amdgcn_mfma_f32_16x16x32_bf16(hf1, Wr[si][kt][2], a2, 0, 0, 0);
          a3 = __builtin_amdgcn_mfma_f32_16x16x32_bf16(hf1, Wr[si][kt][3], a3, 0, 0, 0);
          bf16x8 hf2 = *reinterpret_cast<const bf16x8*>(h2r + kt*512 + afrag);
          bf16x8 wb0 = *reinterpret_cast<const bf16x8*>(&whh2s[s*8192 + (kt*4+0)*512 + afrag]);
          bf16x8 wb1 = *reinterpret_cast<const bf16x8*>(&whh2s[s*8192 + (kt*4+1)*512 + afrag]);
          bf16x8 wb2 = *reinterpret_cast<const bf16x8*>(&whh2s[s*8192 + (kt*4+2)*512 + afrag]);
          bf16x8 wb3 = *reinterpret_cast<const bf16x8*>(&whh2s[s*8192 + (kt*4+3)*512 + afrag]);
          a0 = __builtin_amdgcn_mfma_f32_16x16x32_bf16(hf2, wb0, a0, 0, 0, 0);
          a1 = __builtin_amdgcn_mfma_f32_16x16x32_bf16(hf2, wb1, a1, 0, 0, 0);
          a2 = __builtin_amdgcn_mfma_f32_16x16x32_bf16(hf2, wb2, a2, 0, 0, 0);
          a3 = __builtin_amdgcn_mfma_f32_16x16x32_bf16(hf2, wb3, a3, 0, 0, 0);
        }
        if (t > 0){
          int hwIdx = (2*s + (Llo >> 3))*128 + Lhi*32 + (Llo & 7);
#pragma unroll
          for (int r = 0; r < 4; ++r){
            float iv = sigm(a0[r]);
            float fv = sigm(a1[r]);
            float gv = tanh_(a2[r]);
            float ov = sigm(a3[r]);
            float cn = fv*cr[si][r] + iv*gv;
            cr[si][r] = cn;
            h2w[hwIdx + r*8] = f2bf(ov * tanh_(cn));
          }
        }
      }
      if (w == 4 && t >= 2){
        f32x4 pacc = {boutr, boutr, boutr, boutr};
#pragma unroll
        for (int kt = 0; kt < 4; ++kt){
          bf16x8 ha = *reinterpret_cast<const bf16x8*>(h2r + kt*512 + afrag);
          bf16x8 wb = *reinterpret_cast<const bf16x8*>(&wos[kt*512 + afrag]);
          pacc = __builtin_amdgcn_mfma_f32_16x16x32_bf16(ha, wb, pacc, 0, 0, 0);
        }
        if (Llo < NA){
          size_t o = ((size_t)(t-2)*NB + batch0 + Lhi*4)*NA + Llo;
#pragma unroll
          for (int r = 0; r < 4; ++r) out[o + (size_t)r*NA] = pacc[r];
        }
      }
    }

    bar_lds();
  }

  // ---- epilogue (L2 waves): h2(511); proj(510); then proj(511) ----
  if (w >= 4){
    const u16* h1r = h1s + ((TT+1)&1)*2048;   // h1(511)
    const u16* h2r = h2s + (TT&1)*2048;       // h2(510)
    u16*       h2w = h2s + ((TT+1)&1)*2048;
#pragma unroll
    for (int si = 0; si < 2; ++si){
      int s = (w - 4) + si*4;
      f32x4 a0 = (f32x4){biasr[si][0],biasr[si][0],biasr[si][0],biasr[si][0]};
      f32x4 a1 = (f32x4){biasr[si][1],biasr[si][1],biasr[si][1],biasr[si][1]};
      f32x4 a2 = (f32x4){biasr[si][2],biasr[si][2],biasr[si][2],biasr[si][2]};
      f32x4 a3 = (f32x4){biasr[si][3],biasr[si][3],biasr[si][3],biasr[si][3]};
#pragma unroll
      for (int kt = 0; kt < 4; ++kt){
        bf16x8 hf1 = *reinterpret_cast<const bf16x8*>(h1r + kt*512 + afrag);
        a0 = __builtin_amdgcn_mfma_f32_16x16x32_bf16(hf1, Wr[si][kt][0], a0, 0, 0, 0);
        a1 = __builtin_amdgcn_mfma_f32_16x16x32_bf16(hf1, Wr[si][kt][1], a1, 0, 0, 0);
        a2 = __builtin_amdgcn_mfma_f32_16x16x32_bf16(hf1, Wr[si][kt][2], a2, 0, 0, 0);
        a3 = __builtin_amdgcn_mfma_f32_16x16x32_bf16(hf1, Wr[si][kt][3], a3, 0, 0, 0);
        bf16x8 hf2 = *reinterpret_cast<const bf16x8*>(h2r + kt*512 + afrag);
        bf16x8 wb0 = *reinterpret_cast<const bf16x8*>(&whh2s[s*8192 + (kt*4+0)*512 + afrag]);
        bf16x8 wb1 = *reinterpret_cast<const bf16x8*>(&whh2s[s*8192 + (kt*4+1)*512 + afrag]);
        bf16x8 wb2 = *reinterpret_cast<const bf16x8*>(&whh2s[s*8192 + (kt*4+2)*512 + afrag]);
        bf16x8 wb3 = *reinterpret_cast<const bf16x8*>(&whh2s[s*8192 + (kt*4+3)*512 + afrag]);
        a0 = __builtin_amdgcn_mfma_f32_16x16x32_bf16(hf2, wb0, a0, 0, 0, 0);
        a1 = __builtin_amdgcn_mfma_f32_16x16x32_bf16(hf2, wb1, a1, 0, 0, 0);
        a2 = __builtin_amdgcn_mfma_f32_16x16x32_bf16(hf2, wb2, a2, 0, 0, 0);
        a3 = __builtin_amdgcn_mfma_f32_16x16x32_bf16(hf2, wb3, a3, 0, 0, 0);
      }
      int hwIdx = (2*s + (Llo >> 3))*128 + Lhi*32 + (Llo & 7);
#pragma unroll
      for (int r = 0; r < 4; ++r){
        float iv = sigm(a0[r]);
        float fv = sigm(a1[r]);
        float gv = tanh_(a2[r]);
        float ov = sigm(a3[r]);
        float cn = fv*cr[si][r] + iv*gv;
        cr[si][r] = cn;
        h2w[hwIdx + r*8] = f2bf(ov * tanh_(cn));
      }
    }
    if (w == 4){   // proj(510)
      f32x4 pacc = {boutr, boutr, boutr, boutr};
#pragma unroll
      for (int kt = 0; kt < 4; ++kt){
        bf16x8 ha = *reinterpret_cast<const bf16x8*>(h2r + kt*512 + afrag);
        bf16x8 wb = *reinterpret_cast<const bf16x8*>(&wos[kt*512 + afrag]);
        pacc = __builtin_amdgcn_mfma_f32_16x16x32_bf16(ha, wb, pacc, 0, 0, 0);
      }
      if (Llo < NA){
        size_t o = ((size_t)(TT-2)*NB + batch0 + Lhi*4)*NA + Llo;
#pragma unroll
        for (int r = 0; r < 4; ++r) out[o + (size_t)r*NA] = pacc[r];
      }
    }
  }

  bar_lds();

  if (w == 4){   // proj(511)
    const u16* h2f = h2s + ((TT+1)&1)*2048;
    f32x4 pacc = {boutr, boutr, boutr, boutr};
#pragma unroll
    for (int kt = 0; kt < 4; ++kt){
      bf16x8 ha = *reinterpret_cast<const bf16x8*>(h2f + kt*512 + afrag);
      bf16x8 wb = *reinterpret_cast<const bf16x8*>(&wos[kt*512 + afrag]);
      pacc = __builtin_amdgcn_mfma_f32_16x16x32_bf16(ha, wb, pacc, 0, 0, 0);
    }
    if (Llo < NA){
      size_t o = ((size_t)(TT-1)*NB + batch0 + Lhi*4)*NA + Llo;
#pragma unroll
      for (int r = 0; r < 4; ++r) out[o + (size_t)r*NA] = pacc[r];
    }
  }
}

extern "C" void kernel_launch(void* const* d_in, const int* in_sizes, int n_in,
                              void* d_out, int out_size, void* d_ws, size_t ws_size,
                              hipStream_t stream){
  (void)in_sizes; (void)n_in; (void)out_size; (void)d_ws; (void)ws_size;
  const float* xp   = (const float*)d_in[0];
  const float* wih1 = (const float*)d_in[1];
  const float* whh1 = (const float*)d_in[2];
  const float* bih1 = (const float*)d_in[3];
  const float* bhh1 = (const float*)d_in[4];
  const float* wih2 = (const float*)d_in[5];
  const float* whh2 = (const float*)d_in[6];
  const float* bih2 = (const float*)d_in[7];
  const float* bhh2 = (const float*)d_in[8];
  const float* wout = (const float*)d_in[9];
  const float* bout = (const float*)d_in[10];
  float* outp = (float*)d_out;

  hipLaunchKernelGGL(lstm_fused, dim3(64), dim3(512), 0, stream,
                     xp, whh1, bih1, bhh1, wih1, wih2, whh2, bih2, bhh2, wout, bout,
                     outp);
}